// Round 9
// baseline (66.077 us; speedup 1.0000x reference)
//
#include <hip/hip_runtime.h>
#include <hip/hip_bf16.h>

#define VOCAB 128
#define HIDDEN 128

typedef float f32x4 __attribute__((ext_vector_type(4)));

// Block o computes column o of both tables; threads 0-127 (waves 0,1) do
//   T1[v][o] = sum_h emb[v][h]*W[o][h] + b[o],
// threads 128-255 (waves 2,3) do
//   T2[v][o] = sum_h emb[v][h]*W[o][128+h].
// 'which' is wave-uniform -> W row pointer stays scalar. 128-MAC dot each.
__global__ __launch_bounds__(256) void precompute_tables(
        const float* __restrict__ emb,
        const float* __restrict__ W,
        const float* __restrict__ b,
        float* __restrict__ T1,
        float* __restrict__ T2) {
    __shared__ float es[VOCAB * (HIDDEN + 1)];
    int t = threadIdx.x;
    int o = blockIdx.x;

    // Stage emb: 16384 floats, 256 threads x f32x4 x 16 iters, coalesced.
    for (int i = 0; i < (VOCAB * HIDDEN) / (256 * 4); ++i) {
        int f = (i * 256 + t) * 4;
        f32x4 val = *reinterpret_cast<const f32x4*>(emb + f);
        int v = f >> 7;
        int h = f & 127;
        float* d = es + v * (HIDDEN + 1) + h;   // rows of 128 stay intact
        d[0] = val.x; d[1] = val.y; d[2] = val.z; d[3] = val.w;
    }
    __syncthreads();

    int v = t & 127;
    int which = t >> 7;                          // wave-uniform
    const float* wr = W + o * (2 * HIDDEN) + which * HIDDEN;
    const float* er = es + v * (HIDDEN + 1);
    float s = 0.f;
#pragma unroll 16
    for (int h = 0; h < HIDDEN; ++h)
        s += er[h] * wr[h];
    if (which == 0) T1[v * HIDDEN + o] = s + b[o];
    else            T2[v * HIDDEN + o] = s;
}

// Edge kernel (R4 structure — best measured): 32 lanes per edge, one
// float4 per lane, nt stores (1024 B fully contiguous per wave store;
// a full wave covers 2 consecutive edges = 2 KB contiguous).
// Tables read through L1/L2 (proven non-limiting in R5/R6).
// Grid sweep: 2048 blocks = 58.5-ish, 1024 = 50.7, now 512 (8 waves/CU).
__global__ __launch_bounds__(256) void edge_gather_add(
        const int* __restrict__ z,
        const int* __restrict__ src,
        const int* __restrict__ dst,
        const float* __restrict__ T1,
        const float* __restrict__ T2,
        float* __restrict__ out,
        int E) {
    int total = E * 32;
    int stride = gridDim.x * blockDim.x;
    for (int idx = blockIdx.x * blockDim.x + threadIdx.x; idx < total; idx += stride) {
        int e = idx >> 5;
        int q = idx & 31;
        int zs = z[src[e]];
        int zd = z[dst[e]];
        f32x4 a = *reinterpret_cast<const f32x4*>(T1 + zs * HIDDEN + q * 4);
        f32x4 c = *reinterpret_cast<const f32x4*>(T2 + zd * HIDDEN + q * 4);
        f32x4 r = a + c;
        __builtin_nontemporal_store(r, reinterpret_cast<f32x4*>(out + (size_t)e * HIDDEN + q * 4));
    }
}

extern "C" void kernel_launch(void* const* d_in, const int* in_sizes, int n_in,
                              void* d_out, int out_size, void* d_ws, size_t ws_size,
                              hipStream_t stream) {
    const int*   z    = (const int*)d_in[0];          // [N_NODES]
    const int*   ei   = (const int*)d_in[1];          // [2, E] row-major
    const float* emb  = (const float*)d_in[2];        // [128, 128]
    const float* W    = (const float*)d_in[3];        // [128, 256]
    const float* b    = (const float*)d_in[4];        // [128]
    float*       out  = (float*)d_out;                // [E, 128]

    int E = in_sizes[1] / 2;
    const int* src = ei;
    const int* dst = ei + E;

    float* T1 = (float*)d_ws;                         // 64 KB
    float* T2 = T1 + VOCAB * HIDDEN;                  // 64 KB

    precompute_tables<<<VOCAB, 256, 0, stream>>>(emb, W, b, T1, T2);

    edge_gather_add<<<512, 256, 0, stream>>>(z, src, dst, T1, T2, out, E);
}

// Round 10
// 48.867 us; speedup vs baseline: 1.3522x; 1.3522x over previous
//
#include <hip/hip_runtime.h>
#include <hip/hip_bf16.h>

#define VOCAB 128
#define HIDDEN 128

typedef float f32x4 __attribute__((ext_vector_type(4)));

// Block o computes column o of both tables; threads 0-127 (waves 0,1) do
//   T1[v][o] = sum_h emb[v][h]*W[o][h] + b[o],
// threads 128-255 (waves 2,3) do
//   T2[v][o] = sum_h emb[v][h]*W[o][128+h].
__global__ __launch_bounds__(256) void precompute_tables(
        const float* __restrict__ emb,
        const float* __restrict__ W,
        const float* __restrict__ b,
        float* __restrict__ T1,
        float* __restrict__ T2) {
    __shared__ float es[VOCAB * (HIDDEN + 1)];
    int t = threadIdx.x;
    int o = blockIdx.x;

    for (int i = 0; i < (VOCAB * HIDDEN) / (256 * 4); ++i) {
        int f = (i * 256 + t) * 4;
        f32x4 val = *reinterpret_cast<const f32x4*>(emb + f);
        int v = f >> 7;
        int h = f & 127;
        float* d = es + v * (HIDDEN + 1) + h;
        d[0] = val.x; d[1] = val.y; d[2] = val.z; d[3] = val.w;
    }
    __syncthreads();

    int v = t & 127;
    int which = t >> 7;                          // wave-uniform
    const float* wr = W + o * (2 * HIDDEN) + which * HIDDEN;
    const float* er = es + v * (HIDDEN + 1);
    float s = 0.f;
#pragma unroll 16
    for (int h = 0; h < HIDDEN; ++h)
        s += er[h] * wr[h];
    if (which == 0) T1[v * HIDDEN + o] = s + b[o];
    else            T2[v * HIDDEN + o] = s;
}

// Edge kernel: one wave = 2 consecutive edges per iteration.
// Edge/vocab indices are wave-uniform -> fetched via the SCALAR path
// (s_load, lgkmcnt) by deriving the wave id with readfirstlane. Vector
// path per iteration: 2 table loads + 1 nt-store (2 KB contiguous per
// wave pair of edges). Grid 1024x256 = 16 waves/CU (measured optimum).
#define EDGE_GRID 1024
#define EDGE_BLOCK 256

__global__ __launch_bounds__(EDGE_BLOCK) void edge_gather_add(
        const int* __restrict__ z,
        const int* __restrict__ src,
        const int* __restrict__ dst,
        const float* __restrict__ T1,
        const float* __restrict__ T2,
        float* __restrict__ out,
        int E) {
    int tid  = blockIdx.x * EDGE_BLOCK + threadIdx.x;
    int wid  = __builtin_amdgcn_readfirstlane(tid >> 6);  // uniform wave id
    int lane = threadIdx.x & 63;
    int q4   = (lane & 31) << 2;      // float offset within the 128-row
    int hi   = lane >> 5;             // 0: edge e0, 1: edge e1
    int estep = (EDGE_GRID * EDGE_BLOCK) >> 5;            // 16384 edges/sweep

    for (int e0 = wid * 2; e0 < E; e0 += estep) {
        int e1 = e0 + 1;
        if (e1 >= E) e1 = E - 1;      // scalar clamp (tail safety)
        // Scalar loads (SQC path): edge endpoints + vocab ids.
        int s0 = src[e0], s1 = src[e1];
        int d0 = dst[e0], d1 = dst[e1];
        int zs0 = z[s0], zs1 = z[s1];
        int zd0 = z[d0], zd1 = z[d1];
        // Per-lane select of this half-wave's vocab pair.
        int zs = hi ? zs1 : zs0;
        int zd = hi ? zd1 : zd0;
        f32x4 a = *reinterpret_cast<const f32x4*>(T1 + zs * HIDDEN + q4);
        f32x4 c = *reinterpret_cast<const f32x4*>(T2 + zd * HIDDEN + q4);
        f32x4 r = a + c;
        int eo = e0 + hi;
        if (eo < E)
            __builtin_nontemporal_store(r,
                reinterpret_cast<f32x4*>(out + (size_t)eo * HIDDEN + q4));
    }
}

extern "C" void kernel_launch(void* const* d_in, const int* in_sizes, int n_in,
                              void* d_out, int out_size, void* d_ws, size_t ws_size,
                              hipStream_t stream) {
    const int*   z    = (const int*)d_in[0];          // [N_NODES]
    const int*   ei   = (const int*)d_in[1];          // [2, E] row-major
    const float* emb  = (const float*)d_in[2];        // [128, 128]
    const float* W    = (const float*)d_in[3];        // [128, 256]
    const float* b    = (const float*)d_in[4];        // [128]
    float*       out  = (float*)d_out;                // [E, 128]

    int E = in_sizes[1] / 2;
    const int* src = ei;
    const int* dst = ei + E;

    float* T1 = (float*)d_ws;                         // 64 KB
    float* T2 = T1 + VOCAB * HIDDEN;                  // 64 KB

    precompute_tables<<<VOCAB, 256, 0, stream>>>(emb, W, b, T1, T2);

    edge_gather_add<<<EDGE_GRID, EDGE_BLOCK, 0, stream>>>(z, src, dst, T1, T2, out, E);
}